// Round 4
// baseline (1480.155 us; speedup 1.0000x reference)
//
#include <hip/hip_runtime.h>

// Problem constants (shapes fixed by the reference)
#define HP    1017
#define WP    1017
#define NPIX  (HP*WP)          // 1034289
#define N3    (NPIX/3)         // 344763
#define W_IMG 1024
#define RATE  0.001f
#define EPSV  1e-7f

typedef _Float16 half_t;

// log of guarded t (reference: lg = log(where(t<=0, EPS, t)))
__device__ __forceinline__ float LG(float tv) {
    return logf(tv <= 0.0f ? EPSV : tv);
}

// ---------------------------------------------------------------------------
// init: t0 = tlb = max_c(1 - center/A), and pack img_c = img[:HP,:WP,:] contiguously
// ---------------------------------------------------------------------------
__global__ void init_kernel(const float* __restrict__ img, const float* __restrict__ A,
                            float* __restrict__ img_c, float* __restrict__ t0) {
    int b = blockIdx.x * blockDim.x + threadIdx.x;
    int a = blockIdx.y;
    if (b >= WP) return;
    int m = a * WP + b;
    float A0 = A[0], A1 = A[1], A2 = A[2];
    const float* src = img + ((size_t)a * W_IMG + b) * 3;
    img_c[3*m+0] = src[0]; img_c[3*m+1] = src[1]; img_c[3*m+2] = src[2];
    const float* cen = img + ((size_t)(a+3) * W_IMG + (b+3)) * 3;
    float t = 1.0f - cen[0] / A0;
    t = fmaxf(t, 1.0f - cen[1] / A1);
    t = fmaxf(t, 1.0f - cen[2] / A2);
    t0[m] = t;
}

// ---------------------------------------------------------------------------
// standalone sig (used once, for sig0 from the initial t) -> fp16 sig
// ---------------------------------------------------------------------------
__global__ void sig_kernel(const float* __restrict__ t, const float* __restrict__ img_c,
                           const float* __restrict__ A, half_t* __restrict__ sig) {
    int m = blockIdx.x * blockDim.x + threadIdx.x;
    if (m >= NPIX) return;
    float A0 = A[0], A1 = A[1], A2 = A[2];
    float t0 = t[m];
    float tm = t[m > 0 ? m - 1 : 0];
    float tp = t[m < NPIX-1 ? m + 1 : NPIX-1];
    float r0 = 1.0f / t0, rm = 1.0f / tm, rp = 1.0f / tp;
    int base = 3 * m;
    float fm1 = img_c[m > 0        ? base - 1 : 0];
    float f0  = img_c[base + 0];
    float f1  = img_c[base + 1];
    float f2  = img_c[base + 2];
    float f3  = img_c[m < NPIX - 1 ? base + 3 : base + 2];
    float dm1 = (fm1 - A2) * rm + A2;
    float d0  = (f0  - A0) * r0 + A0;
    float d1  = (f1  - A1) * r0 + A1;
    float d2  = (f2  - A2) * r0 + A2;
    float d3  = (f3  - A0) * rp + A0;
    float y0 = 0.5f * (d1 - dm1);
    float y1 = 0.5f * (d2 - d0);
    float y2 = 0.5f * (d3 - d1);
    if (m == 0      ) y0 = d1 - d0;
    if (m == N3     ) y0 = d1 - d0;
    if (m == 2*N3   ) y0 = d1 - d0;
    if (m == N3 - 1 ) y2 = d2 - d1;
    if (m == 2*N3-1 ) y2 = d2 - d1;
    if (m == NPIX-1 ) y2 = d2 - d1;
    float l2 = sqrtf(y0*y0 + y1*y1 + y2*y2);
    sig[m] = (half_t)(1.0f / (1.0f + expf(48.0f * (l2 - 0.1f))));
}

// ---------------------------------------------------------------------------
// one GD-update stencil at flat index m; logs computed on the fly from t
// ---------------------------------------------------------------------------
__device__ __forceinline__ float tnew2(int m, const float* __restrict__ t,
                                       const half_t* __restrict__ sig) {
    int a = m / WP;
    int b = m - a * WP;
    float tc = t[m];
    float w0 = (tc <= 0.0f) ? EPSV : tc;
    float lgC = logf(w0);
    float acc = 0.0f;
    if (b >= 1) {
        float lgW = (b >= 2) ? LG(t[m-2]) : 0.0f;
        acc += (lgC - lgW) * (float)sig[m-1];
    }
    if (b <= WP-2) {
        float lgE = (b <= WP-3) ? LG(t[m+2]) : 0.0f;
        acc -= (lgE - lgC) * (float)sig[m+1];
    }
    if (a <= HP-2) {
        float lgS = (a <= HP-3) ? LG(t[m+2*WP]) : 0.0f;
        acc += (lgC - lgS) * (float)sig[m+WP];
    }
    if (a >= 1) {
        float lgN = (a >= 2) ? LG(t[m-2*WP]) : 0.0f;
        acc -= (lgN - lgC) * (float)sig[m-WP];
    }
    return w0 - RATE * (2.0f * acc / w0);
}

// ---------------------------------------------------------------------------
// fused iteration: t_new (1:1 coalesced), reciprocals via LDS, then sig of t_new
// ---------------------------------------------------------------------------
__global__ __launch_bounds__(256) void fused_kernel(
    const float* __restrict__ t, const half_t* __restrict__ sig,
    const float* __restrict__ img_c, const float* __restrict__ A,
    float* __restrict__ tout, half_t* __restrict__ sigout)
{
    __shared__ float rl[258];          // rl[k] = 1 / t_new[s - 1 + k]
    const int s   = blockIdx.x * 256;
    const int tid = threadIdx.x;
    const int m   = s + tid;
    const bool active = (m < NPIX);

    float tn = 1.0f, r0 = 1.0f;
    if (active) {
        tn = tnew2(m, t, sig);
        r0 = 1.0f / tn;
        rl[tid + 1] = r0;
        tout[m] = tn;
    }
    if (tid == 0) {                    // left halo (wave 0)
        rl[0] = 1.0f / tnew2(s > 0 ? s - 1 : 0, t, sig);
    } else if (tid == 64) {            // right halo (wave 1, runs in parallel)
        int mr = s + 256; if (mr > NPIX - 1) mr = NPIX - 1;
        rl[257] = 1.0f / tnew2(mr, t, sig);
    }
    __syncthreads();
    if (!active) return;

    const float A0 = A[0], A1 = A[1], A2 = A[2];
    float rm = (m > 0)        ? rl[tid]     : r0;
    float rp = (m < NPIX - 1) ? rl[tid + 2] : r0;
    int base = 3 * m;
    float fm1 = img_c[m > 0        ? base - 1 : 0];
    float f0  = img_c[base + 0];
    float f1  = img_c[base + 1];
    float f2  = img_c[base + 2];
    float f3  = img_c[m < NPIX - 1 ? base + 3 : base + 2];
    float dm1 = (fm1 - A2) * rm + A2;
    float d0  = (f0  - A0) * r0 + A0;
    float d1  = (f1  - A1) * r0 + A1;
    float d2  = (f2  - A2) * r0 + A2;
    float d3  = (f3  - A0) * rp + A0;
    float y0 = 0.5f * (d1 - dm1);
    float y1 = 0.5f * (d2 - d0);
    float y2 = 0.5f * (d3 - d1);
    if (m == 0      ) y0 = d1 - d0;
    if (m == N3     ) y0 = d1 - d0;
    if (m == 2*N3   ) y0 = d1 - d0;
    if (m == N3 - 1 ) y2 = d2 - d1;
    if (m == 2*N3-1 ) y2 = d2 - d1;
    if (m == NPIX-1 ) y2 = d2 - d1;
    float l2 = sqrtf(y0*y0 + y1*y1 + y2*y2);
    sigout[m] = (half_t)(1.0f / (1.0f + expf(48.0f * (l2 - 0.1f))));
}

// ---------------------------------------------------------------------------
// final iteration fused with dehaze output (no neighbor exchange needed)
// ---------------------------------------------------------------------------
__global__ __launch_bounds__(256) void fused_final_kernel(
    const float* __restrict__ t, const half_t* __restrict__ sig,
    const float* __restrict__ img_c, const float* __restrict__ A,
    float* __restrict__ out)
{
    int m = blockIdx.x * blockDim.x + threadIdx.x;
    if (m >= NPIX) return;
    float tn = tnew2(m, t, sig);
    float A0 = A[0], A1 = A[1], A2 = A[2];
    float r = 1.0f / tn;
    out[3*m+0] = (img_c[3*m+0] - A0) * r + A0;
    out[3*m+1] = (img_c[3*m+1] - A1) * r + A1;
    out[3*m+2] = (img_c[3*m+2] - A2) * r + A2;
}

extern "C" void kernel_launch(void* const* d_in, const int* in_sizes, int n_in,
                              void* d_out, int out_size, void* d_ws, size_t ws_size,
                              hipStream_t stream) {
    const float* img = (const float*)d_in[0];
    const float* A   = (const float*)d_in[1];
    // workspace: img_c[3N] f32 | t_a[N] f32 | t_b[N] f32 | sig_a[N] f16 | sig_b[N] f16
    float*  ws    = (float*)d_ws;
    float*  img_c = ws;
    float*  t_a   = ws + (size_t)3 * NPIX;
    float*  t_b   = t_a + NPIX;
    half_t* sig_a = (half_t*)(t_b + NPIX);
    half_t* sig_b = sig_a + NPIX;

    dim3 blk2(256, 1, 1);
    dim3 grd2((WP + 255) / 256, HP, 1);
    int blk1 = 256;
    int grd1 = (NPIX + blk1 - 1) / blk1;   // 4041

    hipLaunchKernelGGL(init_kernel, grd2, blk2, 0, stream, img, A, img_c, t_a);
    hipLaunchKernelGGL(sig_kernel, dim3(grd1), dim3(blk1), 0, stream, t_a, img_c, A, sig_a);

    float*  tsrc = t_a;   float*  tdst = t_b;
    half_t* ssrc = sig_a; half_t* sdst = sig_b;
    for (int it = 0; it < 99; ++it) {
        hipLaunchKernelGGL(fused_kernel, dim3(grd1), dim3(blk1), 0, stream,
                           tsrc, ssrc, img_c, A, tdst, sdst);
        float*  tf = tsrc; tsrc = tdst; tdst = tf;
        half_t* sf = ssrc; ssrc = sdst; sdst = sf;
    }
    // iteration 100 fused with the final dehaze
    hipLaunchKernelGGL(fused_final_kernel, dim3(grd1), dim3(blk1), 0, stream,
                       tsrc, ssrc, img_c, A, (float*)d_out);
}

// Round 5
// 1385.941 us; speedup vs baseline: 1.0680x; 1.0680x over previous
//
#include <hip/hip_runtime.h>

// Problem constants (shapes fixed by the reference)
#define HP    1017
#define WP    1017
#define NPIX  (HP*WP)          // 1034289
#define N3    (NPIX/3)         // 344763
#define W_IMG 1024
#define RATE  0.001f
#define EPSV  1e-7f

typedef _Float16 half_t;

__device__ __forceinline__ float fast_rcp(float x) { return __builtin_amdgcn_rcpf(x); }

// log of guarded t (reference: lg = log(where(t<=0, EPS, t))); hardware v_log_f32
__device__ __forceinline__ float LGf(float tv) {
    return __logf(tv <= 0.0f ? EPSV : tv);
}

// ---------------------------------------------------------------------------
// init: t0 = tlb = max_c(1 - center/A), and pack img_c (fp16) contiguously
// ---------------------------------------------------------------------------
__global__ void init_kernel(const float* __restrict__ img, const float* __restrict__ A,
                            half_t* __restrict__ img_c, float* __restrict__ t0) {
    int b = blockIdx.x * blockDim.x + threadIdx.x;
    int a = blockIdx.y;
    if (b >= WP) return;
    int m = a * WP + b;
    float A0 = A[0], A1 = A[1], A2 = A[2];
    const float* src = img + ((size_t)a * W_IMG + b) * 3;
    img_c[3*m+0] = (half_t)src[0];
    img_c[3*m+1] = (half_t)src[1];
    img_c[3*m+2] = (half_t)src[2];
    const float* cen = img + ((size_t)(a+3) * W_IMG + (b+3)) * 3;
    float t = 1.0f - cen[0] / A0;
    t = fmaxf(t, 1.0f - cen[1] / A1);
    t = fmaxf(t, 1.0f - cen[2] / A2);
    t0[m] = t;
}

// ---------------------------------------------------------------------------
// sig core: given r0/rm/rp (reciprocals of guard pixel, prev, next) compute sig
// ---------------------------------------------------------------------------
__device__ __forceinline__ float sig_at(int m, float r0, float rm, float rp,
                                        const half_t* __restrict__ img_c,
                                        float A0, float A1, float A2) {
    int base = 3 * m;
    float fm1 = (float)img_c[m > 0        ? base - 1 : 0];
    float f0  = (float)img_c[base + 0];
    float f1  = (float)img_c[base + 1];
    float f2  = (float)img_c[base + 2];
    float f3  = (float)img_c[m < NPIX - 1 ? base + 3 : base + 2];
    float dm1 = (fm1 - A2) * rm + A2;
    float d0  = (f0  - A0) * r0 + A0;
    float d1  = (f1  - A1) * r0 + A1;
    float d2  = (f2  - A2) * r0 + A2;
    float d3  = (f3  - A0) * rp + A0;
    float y0 = 0.5f * (d1 - dm1);
    float y1 = 0.5f * (d2 - d0);
    float y2 = 0.5f * (d3 - d1);
    if (m == 0      ) y0 = d1 - d0;
    if (m == N3     ) y0 = d1 - d0;
    if (m == 2*N3   ) y0 = d1 - d0;
    if (m == N3 - 1 ) y2 = d2 - d1;
    if (m == 2*N3-1 ) y2 = d2 - d1;
    if (m == NPIX-1 ) y2 = d2 - d1;
    float l2 = sqrtf(y0*y0 + y1*y1 + y2*y2);
    return fast_rcp(1.0f + __expf(48.0f * (l2 - 0.1f)));
}

// ---------------------------------------------------------------------------
// standalone sig (used once, for sig0 from the initial t) -> fp16 sig
// ---------------------------------------------------------------------------
__global__ void sig_kernel(const float* __restrict__ t, const half_t* __restrict__ img_c,
                           const float* __restrict__ A, half_t* __restrict__ sig) {
    int m = blockIdx.x * blockDim.x + threadIdx.x;
    if (m >= NPIX) return;
    float r0 = fast_rcp(t[m]);
    float rm = fast_rcp(t[m > 0 ? m - 1 : 0]);
    float rp = fast_rcp(t[m < NPIX-1 ? m + 1 : NPIX-1]);
    sig[m] = (half_t)sig_at(m, r0, rm, rp, img_c, A[0], A[1], A[2]);
}

// ---------------------------------------------------------------------------
// GD-update stencil at flat index m; logs on the fly via hardware v_log_f32
// ---------------------------------------------------------------------------
__device__ __forceinline__ float tnew2(int m, const float* __restrict__ t,
                                       const half_t* __restrict__ sig) {
    int a = m / WP;
    int b = m - a * WP;
    float tc = t[m];
    float w0 = (tc <= 0.0f) ? EPSV : tc;
    float lgC = __logf(w0);
    float acc = 0.0f;
    if (b >= 1) {
        float lgW = (b >= 2) ? LGf(t[m-2]) : 0.0f;
        acc += (lgC - lgW) * (float)sig[m-1];
    }
    if (b <= WP-2) {
        float lgE = (b <= WP-3) ? LGf(t[m+2]) : 0.0f;
        acc -= (lgE - lgC) * (float)sig[m+1];
    }
    if (a <= HP-2) {
        float lgS = (a <= HP-3) ? LGf(t[m+2*WP]) : 0.0f;
        acc += (lgC - lgS) * (float)sig[m+WP];
    }
    if (a >= 1) {
        float lgN = (a >= 2) ? LGf(t[m-2*WP]) : 0.0f;
        acc -= (lgN - lgC) * (float)sig[m-WP];
    }
    return w0 - RATE * 2.0f * acc * fast_rcp(w0);
}

// ---------------------------------------------------------------------------
// fused iteration: t_new (1:1 coalesced), reciprocals via LDS, then sig of t_new
// ---------------------------------------------------------------------------
__global__ __launch_bounds__(256) void fused_kernel(
    const float* __restrict__ t, const half_t* __restrict__ sig,
    const half_t* __restrict__ img_c, const float* __restrict__ A,
    float* __restrict__ tout, half_t* __restrict__ sigout)
{
    __shared__ float rl[258];          // rl[k] = 1 / t_new[s - 1 + k]
    const int s   = blockIdx.x * 256;
    const int tid = threadIdx.x;
    const int m   = s + tid;
    const bool active = (m < NPIX);

    float tn = 1.0f, r0 = 1.0f;
    if (active) {
        tn = tnew2(m, t, sig);
        r0 = fast_rcp(tn);
        rl[tid + 1] = r0;
        tout[m] = tn;
    }
    if (tid == 0) {                    // left halo (wave 0)
        rl[0] = fast_rcp(tnew2(s > 0 ? s - 1 : 0, t, sig));
    } else if (tid == 64) {            // right halo (wave 1, runs in parallel)
        int mr = s + 256; if (mr > NPIX - 1) mr = NPIX - 1;
        rl[257] = fast_rcp(tnew2(mr, t, sig));
    }
    __syncthreads();
    if (!active) return;

    float rm = (m > 0)        ? rl[tid]     : r0;
    float rp = (m < NPIX - 1) ? rl[tid + 2] : r0;
    sigout[m] = (half_t)sig_at(m, r0, rm, rp, img_c, A[0], A[1], A[2]);
}

// ---------------------------------------------------------------------------
// final iteration fused with dehaze output (no neighbor exchange needed)
// ---------------------------------------------------------------------------
__global__ __launch_bounds__(256) void fused_final_kernel(
    const float* __restrict__ t, const half_t* __restrict__ sig,
    const half_t* __restrict__ img_c, const float* __restrict__ A,
    float* __restrict__ out)
{
    int m = blockIdx.x * blockDim.x + threadIdx.x;
    if (m >= NPIX) return;
    float tn = tnew2(m, t, sig);
    float A0 = A[0], A1 = A[1], A2 = A[2];
    float r = 1.0f / tn;               // precise div for the final output
    out[3*m+0] = ((float)img_c[3*m+0] - A0) * r + A0;
    out[3*m+1] = ((float)img_c[3*m+1] - A1) * r + A1;
    out[3*m+2] = ((float)img_c[3*m+2] - A2) * r + A2;
}

extern "C" void kernel_launch(void* const* d_in, const int* in_sizes, int n_in,
                              void* d_out, int out_size, void* d_ws, size_t ws_size,
                              hipStream_t stream) {
    const float* img = (const float*)d_in[0];
    const float* A   = (const float*)d_in[1];
    // workspace: t_a[N] f32 | t_b[N] f32 | img_c[3N+pad] f16 | sig_a[N+pad] f16 | sig_b f16
    float*  ws    = (float*)d_ws;
    float*  t_a   = ws;
    float*  t_b   = t_a + NPIX;
    half_t* img_c = (half_t*)(t_b + NPIX);
    half_t* sig_a = img_c + ((size_t)3 * NPIX + 1);   // +1 pad keeps 4B alignment
    half_t* sig_b = sig_a + (NPIX + 1);

    dim3 blk2(256, 1, 1);
    dim3 grd2((WP + 255) / 256, HP, 1);
    int blk1 = 256;
    int grd1 = (NPIX + blk1 - 1) / blk1;   // 4041

    hipLaunchKernelGGL(init_kernel, grd2, blk2, 0, stream, img, A, img_c, t_a);
    hipLaunchKernelGGL(sig_kernel, dim3(grd1), dim3(blk1), 0, stream, t_a, img_c, A, sig_a);

    float*  tsrc = t_a;   float*  tdst = t_b;
    half_t* ssrc = sig_a; half_t* sdst = sig_b;
    for (int it = 0; it < 99; ++it) {
        hipLaunchKernelGGL(fused_kernel, dim3(grd1), dim3(blk1), 0, stream,
                           tsrc, ssrc, img_c, A, tdst, sdst);
        float*  tf = tsrc; tsrc = tdst; tdst = tf;
        half_t* sf = ssrc; ssrc = sdst; sdst = sf;
    }
    // iteration 100 fused with the final dehaze
    hipLaunchKernelGGL(fused_final_kernel, dim3(grd1), dim3(blk1), 0, stream,
                       tsrc, ssrc, img_c, A, (float*)d_out);
}

// Round 6
// 1086.633 us; speedup vs baseline: 1.3621x; 1.2754x over previous
//
#include <hip/hip_runtime.h>

// Problem constants (shapes fixed by the reference)
#define HP    1017
#define WP    1017
#define NPIX  (HP*WP)          // 1034289
#define N3    (NPIX/3)         // 344763
#define W_IMG 1024
#define RATE  0.001f
#define EPSV  1e-7f

typedef _Float16 half_t;

__device__ __forceinline__ float fast_rcp(float x) { return __builtin_amdgcn_rcpf(x); }

// ---------------------------------------------------------------------------
// init: t0 = tlb = max_c(1 - center/A), and pack img_c (fp16) contiguously
// ---------------------------------------------------------------------------
__global__ void init_kernel(const float* __restrict__ img, const float* __restrict__ A,
                            half_t* __restrict__ img_c, float* __restrict__ t0) {
    int b = blockIdx.x * blockDim.x + threadIdx.x;
    int a = blockIdx.y;
    if (b >= WP) return;
    int m = a * WP + b;
    float A0 = A[0], A1 = A[1], A2 = A[2];
    const float* src = img + ((size_t)a * W_IMG + b) * 3;
    img_c[3*m+0] = (half_t)src[0];
    img_c[3*m+1] = (half_t)src[1];
    img_c[3*m+2] = (half_t)src[2];
    const float* cen = img + ((size_t)(a+3) * W_IMG + (b+3)) * 3;
    float t = 1.0f - cen[0] / A0;
    t = fmaxf(t, 1.0f - cen[1] / A1);
    t = fmaxf(t, 1.0f - cen[2] / A2);
    t0[m] = t;
}

// ---------------------------------------------------------------------------
// sig core: given reciprocals r0/rm/rp of (guarded) t at m, m-1, m+1
// ---------------------------------------------------------------------------
__device__ __forceinline__ float sig_at(int m, float r0, float rm, float rp,
                                        const half_t* __restrict__ img_c,
                                        float A0, float A1, float A2) {
    int base = 3 * m;
    float fm1 = (float)img_c[m > 0        ? base - 1 : 0];
    float f0  = (float)img_c[base + 0];
    float f1  = (float)img_c[base + 1];
    float f2  = (float)img_c[base + 2];
    float f3  = (float)img_c[m < NPIX - 1 ? base + 3 : base + 2];
    float dm1 = (fm1 - A2) * rm + A2;
    float d0  = (f0  - A0) * r0 + A0;
    float d1  = (f1  - A1) * r0 + A1;
    float d2  = (f2  - A2) * r0 + A2;
    float d3  = (f3  - A0) * rp + A0;
    float y0 = 0.5f * (d1 - dm1);
    float y1 = 0.5f * (d2 - d0);
    float y2 = 0.5f * (d3 - d1);
    if (m == 0      ) y0 = d1 - d0;
    if (m == N3     ) y0 = d1 - d0;
    if (m == 2*N3   ) y0 = d1 - d0;
    if (m == N3 - 1 ) y2 = d2 - d1;
    if (m == 2*N3-1 ) y2 = d2 - d1;
    if (m == NPIX-1 ) y2 = d2 - d1;
    float l2 = sqrtf(y0*y0 + y1*y1 + y2*y2);
    return fast_rcp(1.0f + __expf(48.0f * (l2 - 0.1f)));
}

// ---------------------------------------------------------------------------
// standalone sig+lg (used once, from the initial t)
// ---------------------------------------------------------------------------
__global__ void sig_kernel(const float* __restrict__ t, const half_t* __restrict__ img_c,
                           const float* __restrict__ A,
                           half_t* __restrict__ sig, float* __restrict__ lgout) {
    int m = blockIdx.x * blockDim.x + threadIdx.x;
    if (m >= NPIX) return;
    float t0 = t[m];
    float r0 = fast_rcp(t0);
    float rm = fast_rcp(t[m > 0 ? m - 1 : 0]);
    float rp = fast_rcp(t[m < NPIX-1 ? m + 1 : NPIX-1]);
    sig[m] = (half_t)sig_at(m, r0, rm, rp, img_c, A[0], A[1], A[2]);
    lgout[m] = __logf(t0 <= 0.0f ? EPSV : t0);
}

// ---------------------------------------------------------------------------
// GD-update stencil at flat index m (R3 structure: reads STORED lg, plain loads)
// ---------------------------------------------------------------------------
__device__ __forceinline__ float tnew_at(int m, const float* __restrict__ t,
                                         const float* __restrict__ lg,
                                         const half_t* __restrict__ sig) {
    int a = m / WP;
    int b = m - a * WP;
    float tc = t[m];
    float w0 = (tc <= 0.0f) ? EPSV : tc;
    float lgC = lg[m];
    float acc = 0.0f;
    if (b >= 1) {
        float lgW = (b >= 2) ? lg[m-2] : 0.0f;
        acc += (lgC - lgW) * (float)sig[m-1];
    }
    if (b <= WP-2) {
        float lgE = (b <= WP-3) ? lg[m+2] : 0.0f;
        acc -= (lgE - lgC) * (float)sig[m+1];
    }
    if (a <= HP-2) {
        float lgS = (a <= HP-3) ? lg[m+2*WP] : 0.0f;
        acc += (lgC - lgS) * (float)sig[m+WP];
    }
    if (a >= 1) {
        float lgN = (a >= 2) ? lg[m-2*WP] : 0.0f;
        acc -= (lgN - lgC) * (float)sig[m-WP];
    }
    return w0 - RATE * 2.0f * acc * fast_rcp(w0);
}

// ---------------------------------------------------------------------------
// fused iteration: t_new (1:1 coalesced), lg_new in phase 1, sig_new via LDS rcp
// ---------------------------------------------------------------------------
__global__ __launch_bounds__(256) void fused_kernel(
    const float* __restrict__ t, const float* __restrict__ lg, const half_t* __restrict__ sig,
    const half_t* __restrict__ img_c, const float* __restrict__ A,
    float* __restrict__ tout, float* __restrict__ lgout, half_t* __restrict__ sigout)
{
    __shared__ float rl[258];          // rl[k] = 1 / t_new[s - 1 + k]
    const int s   = blockIdx.x * 256;
    const int tid = threadIdx.x;
    const int m   = s + tid;
    const bool active = (m < NPIX);

    float tn = 1.0f, r0 = 1.0f;
    if (active) {
        tn = tnew_at(m, t, lg, sig);
        r0 = fast_rcp(tn);
        rl[tid + 1] = r0;
        tout[m]  = tn;
        lgout[m] = __logf(tn <= 0.0f ? EPSV : tn);
    }
    if (tid == 0) {                    // left halo (wave 0)
        rl[0] = fast_rcp(tnew_at(s > 0 ? s - 1 : 0, t, lg, sig));
    } else if (tid == 64) {            // right halo (wave 1, runs in parallel)
        int mr = s + 256; if (mr > NPIX - 1) mr = NPIX - 1;
        rl[257] = fast_rcp(tnew_at(mr, t, lg, sig));
    }
    __syncthreads();
    if (!active) return;

    float rm = (m > 0)        ? rl[tid]     : r0;
    float rp = (m < NPIX - 1) ? rl[tid + 2] : r0;
    sigout[m] = (half_t)sig_at(m, r0, rm, rp, img_c, A[0], A[1], A[2]);
}

// ---------------------------------------------------------------------------
// final iteration fused with dehaze output (no neighbor exchange needed)
// ---------------------------------------------------------------------------
__global__ __launch_bounds__(256) void fused_final_kernel(
    const float* __restrict__ t, const float* __restrict__ lg, const half_t* __restrict__ sig,
    const half_t* __restrict__ img_c, const float* __restrict__ A,
    float* __restrict__ out)
{
    int m = blockIdx.x * blockDim.x + threadIdx.x;
    if (m >= NPIX) return;
    float tn = tnew_at(m, t, lg, sig);
    float A0 = A[0], A1 = A[1], A2 = A[2];
    float r = 1.0f / tn;               // precise div for the final output
    out[3*m+0] = ((float)img_c[3*m+0] - A0) * r + A0;
    out[3*m+1] = ((float)img_c[3*m+1] - A1) * r + A1;
    out[3*m+2] = ((float)img_c[3*m+2] - A2) * r + A2;
}

extern "C" void kernel_launch(void* const* d_in, const int* in_sizes, int n_in,
                              void* d_out, int out_size, void* d_ws, size_t ws_size,
                              hipStream_t stream) {
    const float* img = (const float*)d_in[0];
    const float* A   = (const float*)d_in[1];
    // workspace: t_a,t_b,lg_a,lg_b [N] f32 | img_c[3N] f16 | sig_a,sig_b [N] f16
    float*  ws    = (float*)d_ws;
    float*  t_a   = ws;
    float*  t_b   = t_a + NPIX;
    float*  lg_a  = t_b + NPIX;
    float*  lg_b  = lg_a + NPIX;
    half_t* img_c = (half_t*)(lg_b + NPIX);
    half_t* sig_a = img_c + ((size_t)3 * NPIX + 1);   // +1 pads keep 4B alignment
    half_t* sig_b = sig_a + (NPIX + 1);

    dim3 blk2(256, 1, 1);
    dim3 grd2((WP + 255) / 256, HP, 1);
    int blk1 = 256;
    int grd1 = (NPIX + blk1 - 1) / blk1;   // 4041

    hipLaunchKernelGGL(init_kernel, grd2, blk2, 0, stream, img, A, img_c, t_a);
    hipLaunchKernelGGL(sig_kernel, dim3(grd1), dim3(blk1), 0, stream, t_a, img_c, A, sig_a, lg_a);

    float*  tsrc = t_a;   float*  tdst = t_b;
    float*  gsrc = lg_a;  float*  gdst = lg_b;
    half_t* ssrc = sig_a; half_t* sdst = sig_b;
    for (int it = 0; it < 99; ++it) {
        hipLaunchKernelGGL(fused_kernel, dim3(grd1), dim3(blk1), 0, stream,
                           tsrc, gsrc, ssrc, img_c, A, tdst, gdst, sdst);
        float*  tf = tsrc; tsrc = tdst; tdst = tf;
        float*  gf = gsrc; gsrc = gdst; gdst = gf;
        half_t* sf = ssrc; ssrc = sdst; sdst = sf;
    }
    // iteration 100 fused with the final dehaze
    hipLaunchKernelGGL(fused_final_kernel, dim3(grd1), dim3(blk1), 0, stream,
                       tsrc, gsrc, ssrc, img_c, A, (float*)d_out);
}